// Round 2
// baseline (133.771 us; speedup 1.0000x reference)
//
#include <hip/hip_runtime.h>

// Path signature depth 4, path (N=64, L=512, C=8) fp32.
// Output per batch: levels 1..4 concat -> 8 + 64 + 512 + 4096 = 4680 floats.
//
// R2 structure: barrier-free register-resident recurrence.
//  k1: wave-per-chunk (K=32 chunks/batch, 16 steps each). Lane (a,b) owns
//      S4[a][b][*][*] (64 regs), S3[a][b][*] (8), S2[ab], S1[a]. Increment z
//      is wave-uniform (LDS broadcast); z[a],z[b] via per-lane scalar LDS
//      reads so all register indices stay compile-time constant.
//  k2: 4 waves/batch, each wave serially Chen-combines 8 chunk sigs
//      (A-state in regs; B4 double-buffered in regs, B1-3 staged in LDS with
//      B3 padded to stride 72 to break bank conflicts; next-B prefetched).
//  k3: 1 wave/batch combines the 4 partials -> d_out.

#define NB   64
#define LP   512
#define SIG  4680
#define O2   8
#define O3   72
#define O4   584
#define K1   32
#define SPC  16
#define PAD3 72          // padded b-stride (floats) for staged B3
#define STG  648         // staged B123: 72 + 8*72 floats
#define O4_4 146         // O4/4
#define O3_4 18          // O3/4

// ---------------------------------------------------------------------------
// Phase 1: wave-per-chunk signature.
// Grid: NB*8 blocks of 256 threads; block = 4 consecutive chunks of batch n.
// ---------------------------------------------------------------------------
__global__ __launch_bounds__(256, 2) void k1_chunks(const float* __restrict__ path,
                                                    float* __restrict__ ws)
{
    __shared__ float zbuf[64 * 8];        // 64 increments x 8 dims
    const int tid = threadIdx.x;
    const int n   = blockIdx.x >> 3;
    const int q   = blockIdx.x & 7;
    const int T0  = q * 64;               // first increment index of this block

    // stage increments (float4 granularity, guarded past t=510)
    if (tid < 128) {
        const int t = T0 + (tid >> 1);
        const float4* p4 = (const float4*)path + (size_t)n * (LP * 2);
        float4 z4 = make_float4(0.f, 0.f, 0.f, 0.f);
        if (t < LP - 1) {
            float4 x0 = p4[t * 2 + (tid & 1)];
            float4 x1 = p4[t * 2 + 2 + (tid & 1)];
            z4 = make_float4(x1.x - x0.x, x1.y - x0.y, x1.z - x0.z, x1.w - x0.w);
        }
        ((float4*)zbuf)[tid] = z4;
    }
    __syncthreads();

    const int w = tid >> 6, lane = tid & 63;
    const int a = lane >> 3, b = lane & 7;

    float s1 = 0.f, s2 = 0.f, s3[8], s4[64];
    #pragma unroll
    for (int c = 0; c < 8; ++c) s3[c] = 0.f;
    #pragma unroll
    for (int e = 0; e < 64; ++e) s4[e] = 0.f;

    const float* zw = zbuf + w * (SPC * 8);

    #pragma unroll 4
    for (int s = 0; s < SPC; ++s) {
        const float* zs = zw + s * 8;
        float z[8];
        float4 zl = ((const float4*)zs)[0];
        float4 zh = ((const float4*)zs)[1];
        z[0] = zl.x; z[1] = zl.y; z[2] = zl.z; z[3] = zl.w;
        z[4] = zh.x; z[5] = zh.y; z[6] = zh.z; z[7] = zh.w;
        const float za  = zs[a];          // per-lane LDS read (8-way broadcast)
        const float zbv = zs[b];

        // exp(z) truncated product coefficients (all use OLD state)
        const float B4 = zbv * (za * (1.f/24.f) + s1 * (1.f/6.f)) + s2 * 0.5f;
        const float G3 = zbv * (za * (1.f/6.f)  + s1 * 0.5f)      + s2;

        #pragma unroll
        for (int c = 0; c < 8; ++c) {
            const float Ac = B4 * z[c] + s3[c];
            #pragma unroll
            for (int d = 0; d < 8; ++d) s4[c*8+d] += Ac * z[d];
            s3[c] += G3 * z[c];
        }
        s2 += zbv * (za * 0.5f + s1);
        s1 += za;
    }

    const int chunk = q * 4 + w;
    float* dst = ws + (size_t)(n * K1 + chunk) * SIG;
    if (b == 0) dst[a] = s1;
    dst[O2 + lane] = s2;
    *(float4*)(dst + O3 + lane*8)     = make_float4(s3[0], s3[1], s3[2], s3[3]);
    *(float4*)(dst + O3 + lane*8 + 4) = make_float4(s3[4], s3[5], s3[6], s3[7]);
    float4* d4 = (float4*)(dst + O4) + lane * 16;
    #pragma unroll
    for (int i = 0; i < 16; ++i)
        d4[i] = make_float4(s4[i*4], s4[i*4+1], s4[i*4+2], s4[i*4+3]);
}

// ---------------------------------------------------------------------------
// Phase 2 helpers: wave-level Chen product with A in registers.
// ---------------------------------------------------------------------------
__device__ __forceinline__ void sig_load(const float* __restrict__ src, int lane, int a,
                                         float& a1, float& a2, float a3[8], float a4[64])
{
    a1 = src[a];
    a2 = src[O2 + lane];
    *(float4*)&a3[0] = *(const float4*)(src + O3 + lane*8);
    *(float4*)&a3[4] = *(const float4*)(src + O3 + lane*8 + 4);
    const float4* s4p = (const float4*)(src + O4) + lane * 16;
    #pragma unroll
    for (int i = 0; i < 16; ++i) *(float4*)&a4[i*4] = s4p[i];
}

__device__ __forceinline__ void sig_store(float* __restrict__ dst, int lane, int a, int b,
                                          float a1, float a2,
                                          const float a3[8], const float a4[64])
{
    if (b == 0) dst[a] = a1;
    dst[O2 + lane] = a2;
    *(float4*)(dst + O3 + lane*8)     = make_float4(a3[0], a3[1], a3[2], a3[3]);
    *(float4*)(dst + O3 + lane*8 + 4) = make_float4(a3[4], a3[5], a3[6], a3[7]);
    float4* d4 = (float4*)(dst + O4) + lane * 16;
    #pragma unroll
    for (int i = 0; i < 16; ++i)
        d4[i] = make_float4(a4[i*4], a4[i*4+1], a4[i*4+2], a4[i*4+3]);
}

// issue B1..B3 loads (146 float4) into 3 regs/lane
__device__ __forceinline__ void stage_issue(const float* __restrict__ bsrc, int lane,
                                            float4 sr[3])
{
    const float4* b4p = (const float4*)bsrc;
    #pragma unroll
    for (int r = 0; r < 3; ++r) {
        const int i4 = r * 64 + lane;
        if (r < 2 || i4 < O4_4) sr[r] = b4p[i4];
        else                    sr[r] = make_float4(0.f, 0.f, 0.f, 0.f);
    }
}

// write staged B1..B3 into LDS, B3 padded to stride 72 floats per b-block
__device__ __forceinline__ void stage_write(float* __restrict__ Bl, int lane,
                                            const float4 sr[3])
{
    #pragma unroll
    for (int r = 0; r < 3; ++r) {
        const int i4 = r * 64 + lane;
        if (r < 2 || i4 < O4_4) {
            int d4;
            if (i4 < O3_4) d4 = i4;
            else { const int rel = i4 - O3_4; d4 = O3_4 + (rel >> 4) * (PAD3/4) + (rel & 15); }
            ((float4*)Bl)[d4] = sr[r];
        }
    }
}

// issue the lane's 64 B4 values (16 float4)
__device__ __forceinline__ void b4_issue(const float* __restrict__ bsrc, int lane,
                                         float (&b4)[64])
{
    const float4* p = (const float4*)bsrc + O4_4 + lane * 16;
    #pragma unroll
    for (int i = 0; i < 16; ++i) *(float4*)&b4[i*4] = p[i];
}

// Chen product: A <- A (x) B.  B1-3 in LDS (Bl), B4 in regs (b4).
__device__ __forceinline__ void product(float& a1, float& a2, float a3[8], float a4[64],
                                        const float* __restrict__ Bl,
                                        const float (&b4)[64], int a, int b)
{
    float b1[8];
    *(float4*)&b1[0] = *(const float4*)(Bl);
    *(float4*)&b1[4] = *(const float4*)(Bl + 4);

    // level 4: A4 += B4 + A1*B3[b,c,d] + A2*B2[c,d] + A3[c]*B1[d]
    #pragma unroll
    for (int c = 0; c < 8; ++c) {
        float b3[8], b2[8];
        *(float4*)&b3[0] = *(const float4*)(Bl + O3 + b * PAD3 + c * 8);
        *(float4*)&b3[4] = *(const float4*)(Bl + O3 + b * PAD3 + c * 8 + 4);
        *(float4*)&b2[0] = *(const float4*)(Bl + O2 + c * 8);
        *(float4*)&b2[4] = *(const float4*)(Bl + O2 + c * 8 + 4);
        const float ac = a3[c];
        #pragma unroll
        for (int d = 0; d < 8; ++d)
            a4[c*8+d] += b4[c*8+d] + a1 * b3[d] + a2 * b2[d] + ac * b1[d];
    }
    // level 3: A3[c] += B3[a,b,c] + A1*B2[b,c] + A2*B1[c]
    float b3o[8], b2o[8];
    *(float4*)&b3o[0] = *(const float4*)(Bl + O3 + a * PAD3 + b * 8);
    *(float4*)&b3o[4] = *(const float4*)(Bl + O3 + a * PAD3 + b * 8 + 4);
    *(float4*)&b2o[0] = *(const float4*)(Bl + O2 + b * 8);
    *(float4*)&b2o[4] = *(const float4*)(Bl + O2 + b * 8 + 4);
    #pragma unroll
    for (int c = 0; c < 8; ++c)
        a3[c] += b3o[c] + a1 * b2o[c] + a2 * b1[c];
    // level 2 / 1 (dynamic-index values read from LDS, not register arrays)
    a2 += Bl[O2 + a * 8 + b] + a1 * Bl[b];
    a1 += Bl[a];
}

template<bool PREF>
__device__ __forceinline__ void prod_step(float& a1, float& a2, float a3[8], float a4[64],
                                          float (&b4c)[64], float (&b4n)[64],
                                          const float* cur, float* nxt,
                                          const float* __restrict__ nsrc,
                                          int lane, int a, int b)
{
    if (PREF) {                       // prefetch next B while computing current
        float4 sr[3];
        stage_issue(nsrc, lane, sr);
        b4_issue(nsrc, lane, b4n);
        stage_write(nxt, lane, sr);
    }
    product(a1, a2, a3, a4, cur, b4c, a, b);
    __syncthreads();
}

// ---------------------------------------------------------------------------
// k2: 64 blocks x 256 threads; wave w of block n combines chunks [8w, 8w+8).
// ---------------------------------------------------------------------------
__global__ __launch_bounds__(256, 1) void k2_combine(const float* __restrict__ ws1,
                                                     float* __restrict__ ws2)
{
    __shared__ float Bl[4][2][STG];
    const int tid = threadIdx.x, w = tid >> 6, lane = tid & 63;
    const int a = lane >> 3, b = lane & 7;
    const int n = blockIdx.x;
    const float* base = ws1 + (size_t)n * K1 * SIG;

    float a1, a2, a3[8], a4[64], b4A[64], b4B[64];
    sig_load(base + (size_t)(w * 8) * SIG, lane, a, a1, a2, a3, a4);
    {
        float4 sr[3];
        stage_issue(base + (size_t)(w*8 + 1) * SIG, lane, sr);
        b4_issue  (base + (size_t)(w*8 + 1) * SIG, lane, b4A);
        stage_write(&Bl[w][0][0], lane, sr);
    }
    __syncthreads();

    prod_step<true >(a1,a2,a3,a4, b4A,b4B, &Bl[w][0][0], &Bl[w][1][0], base + (size_t)(w*8+2)*SIG, lane,a,b);
    prod_step<true >(a1,a2,a3,a4, b4B,b4A, &Bl[w][1][0], &Bl[w][0][0], base + (size_t)(w*8+3)*SIG, lane,a,b);
    prod_step<true >(a1,a2,a3,a4, b4A,b4B, &Bl[w][0][0], &Bl[w][1][0], base + (size_t)(w*8+4)*SIG, lane,a,b);
    prod_step<true >(a1,a2,a3,a4, b4B,b4A, &Bl[w][1][0], &Bl[w][0][0], base + (size_t)(w*8+5)*SIG, lane,a,b);
    prod_step<true >(a1,a2,a3,a4, b4A,b4B, &Bl[w][0][0], &Bl[w][1][0], base + (size_t)(w*8+6)*SIG, lane,a,b);
    prod_step<true >(a1,a2,a3,a4, b4B,b4A, &Bl[w][1][0], &Bl[w][0][0], base + (size_t)(w*8+7)*SIG, lane,a,b);
    prod_step<false>(a1,a2,a3,a4, b4A,b4B, &Bl[w][0][0], &Bl[w][1][0], base, lane,a,b);

    sig_store(ws2 + (size_t)(n * 4 + w) * SIG, lane, a, b, a1, a2, a3, a4);
}

// ---------------------------------------------------------------------------
// k3: 64 blocks x 64 threads (1 wave); combine the 4 partials -> d_out.
// ---------------------------------------------------------------------------
__global__ __launch_bounds__(64, 1) void k3_final(const float* __restrict__ ws2,
                                                  float* __restrict__ out)
{
    __shared__ float Bl[2][STG];
    const int lane = threadIdx.x;
    const int a = lane >> 3, b = lane & 7;
    const int n = blockIdx.x;
    const float* base = ws2 + (size_t)n * 4 * SIG;

    float a1, a2, a3[8], a4[64], b4A[64], b4B[64];
    sig_load(base, lane, a, a1, a2, a3, a4);
    {
        float4 sr[3];
        stage_issue(base + (size_t)SIG, lane, sr);
        b4_issue  (base + (size_t)SIG, lane, b4A);
        stage_write(&Bl[0][0], lane, sr);
    }
    __syncthreads();

    prod_step<true >(a1,a2,a3,a4, b4A,b4B, &Bl[0][0], &Bl[1][0], base + 2*(size_t)SIG, lane,a,b);
    prod_step<true >(a1,a2,a3,a4, b4B,b4A, &Bl[1][0], &Bl[0][0], base + 3*(size_t)SIG, lane,a,b);
    prod_step<false>(a1,a2,a3,a4, b4A,b4B, &Bl[0][0], &Bl[1][0], base, lane,a,b);

    sig_store(out + (size_t)n * SIG, lane, a, b, a1, a2, a3, a4);
}

extern "C" void kernel_launch(void* const* d_in, const int* in_sizes, int n_in,
                              void* d_out, int out_size, void* d_ws, size_t ws_size,
                              hipStream_t stream) {
    const float* path = (const float*)d_in[0];
    float* out = (float*)d_out;
    float* ws1 = (float*)d_ws;
    float* ws2 = ws1 + (size_t)NB * K1 * SIG;   // 38.3 MB + 4.8 MB used of ws

    k1_chunks<<<NB * 8, 256, 0, stream>>>(path, ws1);
    k2_combine<<<NB, 256, 0, stream>>>(ws1, ws2);
    k3_final<<<NB, 64, 0, stream>>>(ws2, out);
}

// Round 3
// 73.334 us; speedup vs baseline: 1.8241x; 1.8241x over previous
//
#include <hip/hip_runtime.h>

// Path signature depth 4, path (N=64, L=512, C=8) fp32.
// Output per batch: levels 1..4 concat -> 8 + 64 + 512 + 4096 = 4680 floats.
//
// k1: wave-per-chunk (K=16 chunks/batch, 32 steps). Lane (a,b) owns
//     S4[a][b][*][*] (64 regs) etc. Increments staged in LDS, zero-padded so
//     every chunk runs exactly 32 steps (exp(0) = identity).
// k2: one block/batch, element-parallel serial combine of the 16 chunk sigs.
//     Thread owns 16 L4 elements (regs). A123 in LDS ping-pong, B123 in LDS
//     triple-buffer ring fed by a 2-deep global prefetch pipeline; B4
//     prefetched to registers (3-set ring, statically unrolled).

#define NB 64
#define LP 512
#define SIG 4680
#define O2 8
#define O3 72
#define O4 584
#define O4_4 146        // O4/4 float4s for levels 1..3
#define K1C 16
#define SPC 32

// ---------------------------------------------------------------------------
// k1: 256 blocks x 256 thr; block=(n,Q); wave w -> chunk Q*4+w (32 steps).
// ---------------------------------------------------------------------------
__global__ __launch_bounds__(256, 2) void k1_chunks(const float* __restrict__ path,
                                                    float* __restrict__ ws)
{
    __shared__ float zbuf[128 * 8];
    const int tid = threadIdx.x;
    const int n = blockIdx.x >> 2;
    const int Q = blockIdx.x & 3;

    {   // stage 128 increments (zero-padded past t=510)
        const int r = tid >> 1, h = tid & 1;
        const int t = Q * 128 + r;
        const float4* p4 = (const float4*)path + (size_t)n * (LP * 2);
        float4 z4 = make_float4(0.f, 0.f, 0.f, 0.f);
        if (t < LP - 1) {
            float4 x0 = p4[t * 2 + h];
            float4 x1 = p4[t * 2 + 2 + h];
            z4 = make_float4(x1.x - x0.x, x1.y - x0.y, x1.z - x0.z, x1.w - x0.w);
        }
        ((float4*)zbuf)[tid] = z4;
    }
    __syncthreads();

    const int w = tid >> 6, lane = tid & 63;
    const int a = lane >> 3, b = lane & 7;

    float s1 = 0.f, s2 = 0.f, s3[8], s4[64];
    #pragma unroll
    for (int c = 0; c < 8; ++c) s3[c] = 0.f;
    #pragma unroll
    for (int e = 0; e < 64; ++e) s4[e] = 0.f;

    const float* zw = zbuf + w * (SPC * 8);

    #pragma unroll 4
    for (int s = 0; s < SPC; ++s) {
        const float* zs = zw + s * 8;
        float z[8];
        float4 zl = ((const float4*)zs)[0];
        float4 zh = ((const float4*)zs)[1];
        z[0]=zl.x; z[1]=zl.y; z[2]=zl.z; z[3]=zl.w;
        z[4]=zh.x; z[5]=zh.y; z[6]=zh.z; z[7]=zh.w;
        const float za  = zs[a];
        const float zbv = zs[b];
        const float B4 = zbv * (za * (1.f/24.f) + s1 * (1.f/6.f)) + s2 * 0.5f;
        const float G3 = zbv * (za * (1.f/6.f)  + s1 * 0.5f)      + s2;
        #pragma unroll
        for (int c = 0; c < 8; ++c) {
            const float Ac = B4 * z[c] + s3[c];
            #pragma unroll
            for (int d = 0; d < 8; ++d) s4[c*8+d] += Ac * z[d];
            s3[c] += G3 * z[c];
        }
        s2 += zbv * (za * 0.5f + s1);
        s1 += za;
    }

    const int chunk = Q * 4 + w;
    float* dst = ws + (size_t)(n * K1C + chunk) * SIG;
    if (b == 0) dst[a] = s1;
    dst[O2 + lane] = s2;
    *(float4*)(dst + O3 + lane*8)     = make_float4(s3[0], s3[1], s3[2], s3[3]);
    *(float4*)(dst + O3 + lane*8 + 4) = make_float4(s3[4], s3[5], s3[6], s3[7]);
    float4* d4 = (float4*)(dst + O4) + lane * 16;
    #pragma unroll
    for (int i = 0; i < 16; ++i)
        d4[i] = make_float4(s4[i*4], s4[i*4+1], s4[i*4+2], s4[i*4+3]);
}

// ---------------------------------------------------------------------------
// k2 combine body: A <- A (x) B, element-parallel across 256 threads.
// ---------------------------------------------------------------------------
__device__ __forceinline__ void combine_body(
    float (&a4)[16], const float (&b4)[16],
    const float* Ap, float* Aq, const float* B,
    int tid, int a, int b, int c0, int f0, int p3a, int p3b, int p3c)
{
    // level 4: A4[abcd] += B4 + A3[abc]B1[d] + A2[ab]B2[cd] + A1[a]B3[bcd]
    const float A1   = Ap[a];
    const float A2   = Ap[O2 + a*8 + b];
    const float A3_0 = Ap[O3 + (a*8+b)*8 + c0];
    const float A3_1 = Ap[O3 + (a*8+b)*8 + c0 + 1];
    float b1[8];
    *(float4*)&b1[0] = *(const float4*)(B);
    *(float4*)&b1[4] = *(const float4*)(B + 4);
    float b2r[16], b3r[16];
    *(float4*)&b2r[0]  = *(const float4*)(B + O2 + c0*8);
    *(float4*)&b2r[4]  = *(const float4*)(B + O2 + c0*8 + 4);
    *(float4*)&b2r[8]  = *(const float4*)(B + O2 + c0*8 + 8);
    *(float4*)&b2r[12] = *(const float4*)(B + O2 + c0*8 + 12);
    *(float4*)&b3r[0]  = *(const float4*)(B + O3 + (b*8+c0)*8);
    *(float4*)&b3r[4]  = *(const float4*)(B + O3 + (b*8+c0)*8 + 4);
    *(float4*)&b3r[8]  = *(const float4*)(B + O3 + (b*8+c0)*8 + 8);
    *(float4*)&b3r[12] = *(const float4*)(B + O3 + (b*8+c0)*8 + 12);
    #pragma unroll
    for (int cc = 0; cc < 2; ++cc) {
        const float A3c = cc ? A3_1 : A3_0;
        #pragma unroll
        for (int d = 0; d < 8; ++d)
            a4[cc*8+d] += b4[cc*8+d] + A3c*b1[d] + A2*b2r[cc*8+d] + A1*b3r[cc*8+d];
    }
    // level 3 (2 owned elements f0, f0+1):
    // A3[abc] += B3[abc] + A2[ab]B1[c] + A1[a]B2[bc]
    const float A2p = Ap[O2 + p3a*8 + p3b];
    const float A1p = Ap[p3a];
    const float n3_0 = Ap[O3+f0]   + A2p*B[p3c]   + A1p*B[O2+p3b*8+p3c]   + B[O3+f0];
    const float n3_1 = Ap[O3+f0+1] + A2p*B[p3c+1] + A1p*B[O2+p3b*8+p3c+1] + B[O3+f0+1];
    Aq[O3+f0]   = n3_0;
    Aq[O3+f0+1] = n3_1;
    // level 2 / 1
    if (tid < 64) Aq[O2+tid] = Ap[O2+tid] + Ap[tid>>3]*B[tid&7] + B[O2+tid];
    if (tid < 8)  Aq[tid]    = Ap[tid] + B[tid];
}

// ---------------------------------------------------------------------------
// k2: 64 blocks x 256 thr; serial combine of 16 chunk sigs, 2-deep prefetch.
// ---------------------------------------------------------------------------
__global__ __launch_bounds__(256, 1) void k2_combine(const float* __restrict__ ws,
                                                     float* __restrict__ out)
{
    __shared__ float sA[2][O4];
    __shared__ float sB[3][O4];
    const int tid = threadIdx.x;
    const int n = blockIdx.x;
    const float* base = ws + (size_t)n * K1C * SIG;

    const int a = tid >> 5, b = (tid >> 2) & 7, c0 = (tid & 3) * 2;
    const int f0 = 2 * tid;
    const int p3a = f0 >> 6, p3b = (f0 >> 3) & 7, p3c = f0 & 7;

    float a4[16], rb0[16], rb1[16], rb2[16];
    float4 stgA, stgB, a123;

    {   // A = sig[0]
        const float4* p = (const float4*)(base + O4) + (size_t)tid * 4;
        *(float4*)&a4[0] = p[0]; *(float4*)&a4[4]  = p[1];
        *(float4*)&a4[8] = p[2]; *(float4*)&a4[12] = p[3];
        a123 = make_float4(0.f,0.f,0.f,0.f);
        if (tid < O4_4) a123 = ((const float4*)base)[tid];
    }
    {   // issue B[1] (b123 -> stgA, b4 -> rb1)
        const float* s = base + SIG;
        stgA = make_float4(0.f,0.f,0.f,0.f);
        if (tid < O4_4) stgA = ((const float4*)s)[tid];
        const float4* p = (const float4*)(s + O4) + (size_t)tid * 4;
        *(float4*)&rb1[0] = p[0]; *(float4*)&rb1[4]  = p[1];
        *(float4*)&rb1[8] = p[2]; *(float4*)&rb1[12] = p[3];
    }
    {   // issue B[2] (b123 -> stgB, b4 -> rb2)
        const float* s = base + 2 * SIG;
        stgB = make_float4(0.f,0.f,0.f,0.f);
        if (tid < O4_4) stgB = ((const float4*)s)[tid];
        const float4* p = (const float4*)(s + O4) + (size_t)tid * 4;
        *(float4*)&rb2[0] = p[0]; *(float4*)&rb2[4]  = p[1];
        *(float4*)&rb2[8] = p[2]; *(float4*)&rb2[12] = p[3];
    }
    if (tid < O4_4) { ((float4*)sA[0])[tid] = a123; ((float4*)sB[1])[tid] = stgA; }
    __syncthreads();

    #pragma unroll
    for (int m = 1; m <= 15; ++m) {
        // issue B[m+2]: b123 -> stg[(m+2)&1], b4 -> rb[(m+2)%3]
        if (m <= 13) {
            const float* s = base + (size_t)(m + 2) * SIG;
            float4 v = make_float4(0.f,0.f,0.f,0.f);
            if (tid < O4_4) v = ((const float4*)s)[tid];
            if (m & 1) stgA = v; else stgB = v;
            const float4* p = (const float4*)(s + O4) + (size_t)tid * 4;
            float4 q0 = p[0], q1 = p[1], q2 = p[2], q3 = p[3];
            const int r = (m + 2) % 3;
            if (r == 0)      { *(float4*)&rb0[0]=q0; *(float4*)&rb0[4]=q1; *(float4*)&rb0[8]=q2; *(float4*)&rb0[12]=q3; }
            else if (r == 1) { *(float4*)&rb1[0]=q0; *(float4*)&rb1[4]=q1; *(float4*)&rb1[8]=q2; *(float4*)&rb1[12]=q3; }
            else             { *(float4*)&rb2[0]=q0; *(float4*)&rb2[4]=q1; *(float4*)&rb2[8]=q2; *(float4*)&rb2[12]=q3; }
        }
        // compute with B[m] (LDS ring slot m%3, reg ring rb[m%3])
        const float* Ap = sA[(m - 1) & 1];
        float* Aq = sA[m & 1];
        const int bc = m % 3;
        const float* B = (bc == 0) ? sB[0] : (bc == 1) ? sB[1] : sB[2];
        if (bc == 0)      combine_body(a4, rb0, Ap, Aq, B, tid, a, b, c0, f0, p3a, p3b, p3c);
        else if (bc == 1) combine_body(a4, rb1, Ap, Aq, B, tid, a, b, c0, f0, p3a, p3b, p3c);
        else              combine_body(a4, rb2, Ap, Aq, B, tid, a, b, c0, f0, p3a, p3b, p3c);
        // write staged b123[m+1] into its LDS ring slot
        if (m <= 14) {
            const int rn = (m + 1) % 3;
            float* Bn = (rn == 0) ? sB[0] : (rn == 1) ? sB[1] : sB[2];
            if (tid < O4_4) ((float4*)Bn)[tid] = (m & 1) ? stgB : stgA;
        }
        __syncthreads();
    }

    float* dst = out + (size_t)n * SIG;
    {
        float4* p = (float4*)(dst + O4) + (size_t)tid * 4;
        p[0] = *(float4*)&a4[0]; p[1] = *(float4*)&a4[4];
        p[2] = *(float4*)&a4[8]; p[3] = *(float4*)&a4[12];
    }
    if (tid < O4_4) ((float4*)dst)[tid] = ((const float4*)sA[1])[tid];
}

extern "C" void kernel_launch(void* const* d_in, const int* in_sizes, int n_in,
                              void* d_out, int out_size, void* d_ws, size_t ws_size,
                              hipStream_t stream) {
    const float* path = (const float*)d_in[0];
    float* out = (float*)d_out;
    float* ws  = (float*)d_ws;   // 64*16*4680*4 B = 19.2 MB used

    k1_chunks<<<NB * 4, 256, 0, stream>>>(path, ws);
    k2_combine<<<NB, 256, 0, stream>>>(ws, out);
}

// Round 4
// 19.932 us; speedup vs baseline: 6.7115x; 3.6793x over previous
//
#include <hip/hip_runtime.h>

// Path signature depth 4, path (N=64, L=512, C=8) fp32.
// Output per batch: levels 1..4 concat -> 8 + 64 + 512 + 4096 = 4680 floats.
//
// k1: 256 blocks = (batch n, group g). Wave w computes chunk (g*4+w) signature
//     (32 Chen steps, state fully in registers: lane (a,b) owns S4[a][b][*][*]).
//     The 4 sigs are exchanged through LDS (L4 in a transposed conflict-free
//     layout) and combined in-block element-parallel (3 Chen products).
//     Result (1/4 of a batch) -> ws, with L4 stored in the same transposed
//     layout so k2's global reads are coalesced.
// k2: 64 blocks; combines the 4 partials -> out (true flat layout).
//
// Combine ownership: thread (w = tid>>6, l = tid&63, a=l>>3, b=l&7) owns the
// 16 L4 elements (a, b, c in {2w, 2w+1}, d=0..7); L3 elements 2*tid, 2*tid+1.
// Transposed L4 layout: float4 #f of the flat L4 (f = lane*16 + i) lives at
// T-index i*64 + lane  ->  owner thread (w,l) accesses T[(w*4+k)*64 + l].

#define NB 64
#define LP 512
#define SIG 4680
#define O2 8
#define O3 72
#define O4 584
#define L123_F4 146      // 584/4

// ---------------------------------------------------------------------------
// Chen product core: a4 (regs, ownership above) + L123 via LDS.
// Ap/Aq: L123 ping-pong (584 floats). B: L123 of right factor. b4: B's L4
// elements owned by this thread.  A <- A (x) B.
// ---------------------------------------------------------------------------
__device__ __forceinline__ void prod_core(
    float (&a4)[16], const float (&b4)[16],
    const float* Ap, float* Aq, const float* B,
    int tid, int w, int l, int a, int b)
{
    const int c0 = 2 * w;
    // level 4: A4[abcd] += B4 + A3[abc]B1[d] + A2[ab]B2[cd] + A1[a]B3[bcd]
    const float A1   = Ap[a];
    const float A2   = Ap[O2 + a * 8 + b];
    const float A3_0 = Ap[O3 + (a * 8 + b) * 8 + c0];
    const float A3_1 = Ap[O3 + (a * 8 + b) * 8 + c0 + 1];
    float b1[8];
    *(float4*)&b1[0] = *(const float4*)(B);
    *(float4*)&b1[4] = *(const float4*)(B + 4);
    float b2r[16], b3r[16];        // B2[c0..c0+1][*] (wave-uniform), B3[b][c0..c0+1][*]
    #pragma unroll
    for (int i = 0; i < 4; ++i) {
        *(float4*)&b2r[4 * i] = *(const float4*)(B + O2 + c0 * 8 + 4 * i);
        *(float4*)&b3r[4 * i] = *(const float4*)(B + O3 + (b * 8 + c0) * 8 + 4 * i);
    }
    #pragma unroll
    for (int cc = 0; cc < 2; ++cc) {
        const float A3c = cc ? A3_1 : A3_0;
        #pragma unroll
        for (int d = 0; d < 8; ++d)
            a4[cc * 8 + d] += b4[cc * 8 + d] + A3c * b1[d]
                            + A2 * b2r[cc * 8 + d] + A1 * b3r[cc * 8 + d];
    }
    // level 3 (elements f0, f0+1): A3[pqr] += B3 + A2[pq]B1[r] + A1[p]B2[qr]
    const int f0 = 2 * tid;
    const int pp = f0 >> 6, qq = (f0 >> 3) & 7, rr = f0 & 7;
    const float A1p  = Ap[pp];
    const float A2pq = Ap[O2 + pp * 8 + qq];
    Aq[O3 + f0]     = Ap[O3 + f0]     + B[O3 + f0]
                    + A2pq * B[rr]     + A1p * B[O2 + qq * 8 + rr];
    Aq[O3 + f0 + 1] = Ap[O3 + f0 + 1] + B[O3 + f0 + 1]
                    + A2pq * B[rr + 1] + A1p * B[O2 + qq * 8 + rr + 1];
    // level 2 / 1
    if (tid < 64) Aq[O2 + tid] = Ap[O2 + tid] + B[O2 + tid] + Ap[tid >> 3] * B[tid & 7];
    if (tid < 8)  Aq[tid] = Ap[tid] + B[tid];
}

// ---------------------------------------------------------------------------
// k1: chunk signatures + in-block 4-way combine.
// ---------------------------------------------------------------------------
__global__ __launch_bounds__(256) void k1_sig4(const float* __restrict__ path,
                                               float* __restrict__ ws)
{
    __shared__ __align__(16) float zbuf[128 * 8];
    __shared__ __align__(16) float sL[4][584];     // L123 of the 4 chunk sigs
    __shared__ float4 sT[4][1024];                 // L4 (transposed layout)
    __shared__ __align__(16) float sA[2][584];     // A-L123 ping-pong

    const int tid = threadIdx.x;
    const int n = blockIdx.x >> 2;
    const int g = blockIdx.x & 3;

    {   // stage 128 increments (zero-padded past t=510; exp(0) = identity)
        const int r = tid >> 1, h = tid & 1;
        const int t = g * 128 + r;
        const float4* p4 = (const float4*)path + (size_t)n * (LP * 2);
        float4 z4 = make_float4(0.f, 0.f, 0.f, 0.f);
        if (t < LP - 1) {
            float4 x0 = p4[t * 2 + h];
            float4 x1 = p4[t * 2 + 2 + h];
            z4 = make_float4(x1.x - x0.x, x1.y - x0.y, x1.z - x0.z, x1.w - x0.w);
        }
        ((float4*)zbuf)[tid] = z4;
    }
    __syncthreads();

    const int w = tid >> 6, l = tid & 63;
    const int a = l >> 3, b = l & 7;

    // ---- chunk signature, 32 steps, state in registers ----
    float s1 = 0.f, s2 = 0.f, s3[8], s4[64];
    #pragma unroll
    for (int c = 0; c < 8; ++c) s3[c] = 0.f;
    #pragma unroll
    for (int e = 0; e < 64; ++e) s4[e] = 0.f;

    const float* zw = zbuf + w * (32 * 8);
    #pragma unroll 4
    for (int s = 0; s < 32; ++s) {
        const float* zs = zw + s * 8;
        float z[8];
        float4 zl = ((const float4*)zs)[0];
        float4 zh = ((const float4*)zs)[1];
        z[0]=zl.x; z[1]=zl.y; z[2]=zl.z; z[3]=zl.w;
        z[4]=zh.x; z[5]=zh.y; z[6]=zh.z; z[7]=zh.w;
        const float za  = zs[a];
        const float zbv = zs[b];
        const float B4 = zbv * (za * (1.f/24.f) + s1 * (1.f/6.f)) + s2 * 0.5f;
        const float G3 = zbv * (za * (1.f/6.f)  + s1 * 0.5f)      + s2;
        #pragma unroll
        for (int c = 0; c < 8; ++c) {
            const float Ac = B4 * z[c] + s3[c];
            #pragma unroll
            for (int d = 0; d < 8; ++d) s4[c*8+d] += Ac * z[d];
            s3[c] += G3 * z[c];
        }
        s2 += zbv * (za * 0.5f + s1);
        s1 += za;
    }

    // ---- publish sig w to LDS ----
    if (b == 0) sL[w][a] = s1;
    sL[w][O2 + l] = s2;
    *(float4*)&sL[w][O3 + l * 8]     = make_float4(s3[0], s3[1], s3[2], s3[3]);
    *(float4*)&sL[w][O3 + l * 8 + 4] = make_float4(s3[4], s3[5], s3[6], s3[7]);
    #pragma unroll
    for (int i = 0; i < 16; ++i)
        sT[w][i * 64 + l] = make_float4(s4[4*i], s4[4*i+1], s4[4*i+2], s4[4*i+3]);
    __syncthreads();

    // ---- in-block combine: A = sig0 (x) sig1 (x) sig2 (x) sig3 ----
    float a4[16], b4[16];
    #pragma unroll
    for (int k = 0; k < 4; ++k) {
        float4 v = sT[0][(w * 4 + k) * 64 + l];
        a4[4*k] = v.x; a4[4*k+1] = v.y; a4[4*k+2] = v.z; a4[4*k+3] = v.w;
    }
    #pragma unroll
    for (int k = 0; k < 4; ++k) {
        float4 v = sT[1][(w * 4 + k) * 64 + l];
        b4[4*k] = v.x; b4[4*k+1] = v.y; b4[4*k+2] = v.z; b4[4*k+3] = v.w;
    }
    prod_core(a4, b4, sL[0], sA[0], sL[1], tid, w, l, a, b);
    __syncthreads();
    #pragma unroll
    for (int k = 0; k < 4; ++k) {
        float4 v = sT[2][(w * 4 + k) * 64 + l];
        b4[4*k] = v.x; b4[4*k+1] = v.y; b4[4*k+2] = v.z; b4[4*k+3] = v.w;
    }
    prod_core(a4, b4, sA[0], sA[1], sL[2], tid, w, l, a, b);
    __syncthreads();
    #pragma unroll
    for (int k = 0; k < 4; ++k) {
        float4 v = sT[3][(w * 4 + k) * 64 + l];
        b4[4*k] = v.x; b4[4*k+1] = v.y; b4[4*k+2] = v.z; b4[4*k+3] = v.w;
    }
    prod_core(a4, b4, sA[1], sA[0], sL[3], tid, w, l, a, b);
    __syncthreads();

    // ---- store partial sig (L4 in transposed layout) ----
    float* dst = ws + (size_t)blockIdx.x * SIG;
    if (tid < L123_F4) ((float4*)dst)[tid] = ((const float4*)sA[0])[tid];
    float4* dT = (float4*)(dst + O4);
    #pragma unroll
    for (int k = 0; k < 4; ++k)
        dT[(w * 4 + k) * 64 + l] = make_float4(a4[4*k], a4[4*k+1], a4[4*k+2], a4[4*k+3]);
}

// ---------------------------------------------------------------------------
// k2: combine the 4 partials of each batch -> out (true flat layout).
// ---------------------------------------------------------------------------
__global__ __launch_bounds__(256) void k2_final(const float* __restrict__ ws,
                                                float* __restrict__ out)
{
    __shared__ __align__(16) float sL[4][584];
    __shared__ __align__(16) float sA[2][584];

    const int tid = threadIdx.x;
    const int n = blockIdx.x;
    const int w = tid >> 6, l = tid & 63;
    const int a = l >> 3, b = l & 7;
    const float* base = ws + (size_t)n * 4 * SIG;

    // stage L123 of all 4 partials
    #pragma unroll
    for (int s = 0; s < 4; ++s)
        if (tid < L123_F4)
            ((float4*)sL[s])[tid] = ((const float4*)(base + (size_t)s * SIG))[tid];

    // own L4 elements: sig0 -> a4; sigs 1..3 -> rb (coalesced T-layout reads)
    float a4[16], rb1[16], rb2[16], rb3[16];
    #pragma unroll
    for (int k = 0; k < 4; ++k) {
        const int ti = (w * 4 + k) * 64 + l;
        float4 v0 = ((const float4*)(base + O4))[ti];
        float4 v1 = ((const float4*)(base + SIG + O4))[ti];
        float4 v2 = ((const float4*)(base + 2 * SIG + O4))[ti];
        float4 v3 = ((const float4*)(base + 3 * SIG + O4))[ti];
        a4[4*k]=v0.x; a4[4*k+1]=v0.y; a4[4*k+2]=v0.z; a4[4*k+3]=v0.w;
        rb1[4*k]=v1.x; rb1[4*k+1]=v1.y; rb1[4*k+2]=v1.z; rb1[4*k+3]=v1.w;
        rb2[4*k]=v2.x; rb2[4*k+1]=v2.y; rb2[4*k+2]=v2.z; rb2[4*k+3]=v2.w;
        rb3[4*k]=v3.x; rb3[4*k+1]=v3.y; rb3[4*k+2]=v3.z; rb3[4*k+3]=v3.w;
    }
    __syncthreads();

    prod_core(a4, rb1, sL[0], sA[0], sL[1], tid, w, l, a, b);
    __syncthreads();
    prod_core(a4, rb2, sA[0], sA[1], sL[2], tid, w, l, a, b);
    __syncthreads();
    prod_core(a4, rb3, sA[1], sA[0], sL[3], tid, w, l, a, b);
    __syncthreads();

    // store final signature in TRUE flat layout
    float* dst = out + (size_t)n * SIG;
    if (tid < L123_F4) ((float4*)dst)[tid] = ((const float4*)sA[0])[tid];
    float4* d4 = (float4*)(dst + O4);
    #pragma unroll
    for (int k = 0; k < 4; ++k)
        d4[l * 16 + w * 4 + k] = make_float4(a4[4*k], a4[4*k+1], a4[4*k+2], a4[4*k+3]);
}

extern "C" void kernel_launch(void* const* d_in, const int* in_sizes, int n_in,
                              void* d_out, int out_size, void* d_ws, size_t ws_size,
                              hipStream_t stream) {
    const float* path = (const float*)d_in[0];
    float* out = (float*)d_out;
    float* ws  = (float*)d_ws;   // 256 * 4680 * 4 B = 4.79 MB used

    k1_sig4<<<NB * 4, 256, 0, stream>>>(path, ws);
    k2_final<<<NB, 256, 0, stream>>>(ws, out);
}